// Round 1
// baseline (899.773 us; speedup 1.0000x reference)
//
#include <hip/hip_runtime.h>
#include <hip/hip_bf16.h>
#include <math.h>

#define E 4
#define B 8192
#define F 2048
#define L 100
#define NROWS (E * B)          // 32768
#define BSPLIT 4
#define ROWS_PER_SPLIT (B / BSPLIT)  // 2048
#define FC 128                 // feature chunk for sums kernel
#define NFC (F / FC)           // 16
#define LAMBDA 1.0f

// ---------------- K1: per-env label histogram -> counts[E*L] ----------------
__global__ void k_counts(const int* __restrict__ y, int* __restrict__ counts) {
    __shared__ int hist[L];
    int e = blockIdx.x;
    for (int i = threadIdx.x; i < L; i += blockDim.x) hist[i] = 0;
    __syncthreads();
    for (int b = threadIdx.x; b < B; b += blockDim.x)
        atomicAdd(&hist[y[e * B + b]], 1);
    __syncthreads();
    for (int i = threadIdx.x; i < L; i += blockDim.x)
        counts[e * L + i] = hist[i];
}

// ---- K2: partial label-masked sums. Grid = BSPLIT*NFC*E = 256 blocks. ------
// Each block: one env e, one feature chunk [f0, f0+128), one batch slice of
// 2048 rows. LDS accumulator [L][FC] with float atomics (lanes cover distinct
// f, so contention only across row-groups landing on the same label).
__global__ void __launch_bounds__(256) k_sums(const float* __restrict__ feats,
                                              const int* __restrict__ y,
                                              float* __restrict__ partial) {
    __shared__ float acc[L * FC];  // 51200 B
    int bs = blockIdx.x & 3;           // batch split 0..3
    int fc = (blockIdx.x >> 2) & 15;   // feature chunk 0..15
    int e  = blockIdx.x >> 6;          // env 0..3
    int f0 = fc * FC;
    int t = threadIdx.x;
    for (int i = t; i < L * FC; i += 256) acc[i] = 0.f;
    __syncthreads();

    int rg = t >> 5;      // row group 0..7
    int lane = t & 31;    // covers 128 floats via float4
    int b_base = bs * ROWS_PER_SPLIT;
    const float* fbase = feats + (size_t)e * B * F + f0 + lane * 4;
    const int* ybase = y + e * B + b_base;

    for (int it = 0; it < ROWS_PER_SPLIT / 8; it += 2) {
        int b1 = it * 8 + rg;
        int b2 = b1 + 8;
        int l1 = ybase[b1];
        int l2 = ybase[b2];
        float4 x1 = *(const float4*)(fbase + (size_t)(b_base + b1) * F);
        float4 x2 = *(const float4*)(fbase + (size_t)(b_base + b2) * F);
        float* p1 = &acc[l1 * FC + lane * 4];
        atomicAdd(p1 + 0, x1.x); atomicAdd(p1 + 1, x1.y);
        atomicAdd(p1 + 2, x1.z); atomicAdd(p1 + 3, x1.w);
        float* p2 = &acc[l2 * FC + lane * 4];
        atomicAdd(p2 + 0, x2.x); atomicAdd(p2 + 1, x2.y);
        atomicAdd(p2 + 2, x2.z); atomicAdd(p2 + 3, x2.w);
    }
    __syncthreads();

    size_t base = ((size_t)(bs * E + e) * L) * F;
    for (int i = t; i < L * FC; i += 256) {
        int l = i / FC, f = i % FC;
        partial[base + (size_t)l * F + f0 + f] = acc[i];
    }
}

// -------- K3: reduce partials -> per-(e,l) variance over feature dim --------
__global__ void k_var(const float* __restrict__ partial,
                      const int* __restrict__ counts,
                      float* __restrict__ var_out) {
    int el = blockIdx.x;  // e*L + l
    int e = el / L, l = el % L;
    int t = threadIdx.x;
    float inv = 1.f / fmaxf((float)counts[el], 1.f);
    float sm = 0.f, sm2 = 0.f;
    for (int f = t; f < F; f += 256) {
        float s = 0.f;
        for (int sp = 0; sp < BSPLIT; ++sp)
            s += partial[(((size_t)(sp * E + e)) * L + l) * F + f];
        float m = s * inv;
        sm += m; sm2 += m * m;
    }
    __shared__ float r1[256], r2[256];
    r1[t] = sm; r2[t] = sm2;
    __syncthreads();
    for (int s = 128; s > 0; s >>= 1) {
        if (t < s) { r1[t] += r1[t + s]; r2[t] += r2[t + s]; }
        __syncthreads();
    }
    if (t == 0) {
        float S = r1[0], S2 = r2[0];
        var_out[el] = (S2 - S * S / (float)F) / (float)(F - 1);
    }
}

// ------------- K5: fp32 tiled GEMM (32768x2048 @ 2048x100) + CE -------------
#define KC 32
#define BM 64
#define BN 128  // 100 padded to 128

__global__ void __launch_bounds__(256) k_gemm_ce(const float* __restrict__ feats,
                                                 const float* __restrict__ Wm,
                                                 const float* __restrict__ bias,
                                                 const int* __restrict__ y,
                                                 float* __restrict__ ce_accum) {
    __shared__ float smem[BM * 132];   // 33792 B; overlays A(2048)+W(4096) tiles
    float* As = smem;                  // [KC][BM] (k-major, transposed)
    float* Ws = smem + KC * BM;        // [KC][BN]
    int t = threadIdx.x;
    int row0 = blockIdx.x * BM;
    int cg = t & 15, rg = t >> 4;      // 16 col-groups x 16 row-groups
    float acc[4][8];
#pragma unroll
    for (int i = 0; i < 4; ++i)
#pragma unroll
        for (int j = 0; j < 8; ++j) acc[i][j] = 0.f;

    int ar = t >> 3;   // 0..31 (plus +32 for second half)
    int akq = t & 7;   // k quad 0..7
    int wkk = t >> 3;  // 0..31
    int wtc = t & 7;

    for (int k0 = 0; k0 < F; k0 += KC) {
        // A tile: rows [row0, row0+64), k in [k0, k0+32), stored [kk][r]
        {
            float4 v0 = *(const float4*)&feats[(size_t)(row0 + ar) * F + k0 + akq * 4];
            float4 v1 = *(const float4*)&feats[(size_t)(row0 + ar + 32) * F + k0 + akq * 4];
            As[(akq * 4 + 0) * BM + ar] = v0.x;
            As[(akq * 4 + 1) * BM + ar] = v0.y;
            As[(akq * 4 + 2) * BM + ar] = v0.z;
            As[(akq * 4 + 3) * BM + ar] = v0.w;
            As[(akq * 4 + 0) * BM + ar + 32] = v1.x;
            As[(akq * 4 + 1) * BM + ar + 32] = v1.y;
            As[(akq * 4 + 2) * BM + ar + 32] = v1.z;
            As[(akq * 4 + 3) * BM + ar + 32] = v1.w;
        }
        // W tile: [kk][c], c padded to 128 with zeros
#pragma unroll
        for (int j2 = 0; j2 < 4; ++j2) {
            int c = (wtc + j2 * 8) * 4;  // 0..124, multiple of 4
            float4 v;
            if (c < 100) v = *(const float4*)&Wm[(size_t)(k0 + wkk) * L + c];
            else         v = make_float4(0.f, 0.f, 0.f, 0.f);
            *(float4*)&Ws[wkk * BN + c] = v;
        }
        __syncthreads();
#pragma unroll 8
        for (int kk = 0; kk < KC; ++kk) {
            float4 a  = *(float4*)&As[kk * BM + rg * 4];
            float4 b0 = *(float4*)&Ws[kk * BN + cg * 8];
            float4 b1 = *(float4*)&Ws[kk * BN + cg * 8 + 4];
            float av[4] = {a.x, a.y, a.z, a.w};
            float bv[8] = {b0.x, b0.y, b0.z, b0.w, b1.x, b1.y, b1.z, b1.w};
#pragma unroll
            for (int i = 0; i < 4; ++i)
#pragma unroll
                for (int j = 0; j < 8; ++j) acc[i][j] += av[i] * bv[j];
        }
        __syncthreads();
    }

    // epilogue: + bias, stash logits in smem [BM][132] (133 would break f4; 132
    // gives (r*132+c) mod 32 = (4r+c) mod 32 -> conflicts only mild on scan)
    float bb[8];
#pragma unroll
    for (int j = 0; j < 8; ++j) {
        int c = cg * 8 + j;
        bb[j] = (c < 100) ? bias[c] : 0.f;
    }
#pragma unroll
    for (int i = 0; i < 4; ++i)
#pragma unroll
        for (int j = 0; j < 8; ++j)
            smem[(rg * 4 + i) * 132 + cg * 8 + j] = acc[i][j] + bb[j];
    __syncthreads();

    float loss = 0.f;
    if (t < BM) {
        const float* Lr = &smem[t * 132];
        float m = -1e30f;
        for (int c = 0; c < 100; ++c) m = fmaxf(m, Lr[c]);
        float s = 0.f;
        for (int c = 0; c < 100; ++c) s += expf(Lr[c] - m);
        int lab = y[row0 + t];
        loss = m + logf(s) - Lr[lab];
    }
    if (t < 64) {
#pragma unroll
        for (int off = 32; off > 0; off >>= 1)
            loss += __shfl_down(loss, off);
        if (t == 0) atomicAdd(ce_accum, loss);
    }
}

// ------------------------- K6: final scalar combine -------------------------
__global__ void k_final(const int* __restrict__ counts,
                        const float* __restrict__ var_in,
                        const float* __restrict__ ce_accum,
                        float* __restrict__ out) {
    __shared__ float s_sum[128], s_cnt[128];
    int t = threadIdx.x;
    float selsum = 0.f, selcnt = 0.f;
    for (int l = t; l < L; l += 128) {
        float nvis = 0.f, vsum = 0.f;
        for (int e = 0; e < E; ++e) {
            if (counts[e * L + l] > 0) { nvis += 1.f; vsum += var_in[e * L + l]; }
        }
        float per_label = vsum / fmaxf(nvis, 1.f);
        if (nvis > 1.5f) { selsum += per_label; selcnt += 1.f; }
    }
    s_sum[t] = selsum; s_cnt[t] = selcnt;
    __syncthreads();
    for (int s = 64; s > 0; s >>= 1) {
        if (t < s) { s_sum[t] += s_sum[t + s]; s_cnt[t] += s_cnt[t + s]; }
        __syncthreads();
    }
    if (t == 0) {
        float mean_loss = LAMBDA * s_sum[0] / fmaxf(s_cnt[0], 1.f);
        float ce = ce_accum[0] / (float)NROWS;
        out[0] = mean_loss + ce;
    }
}

extern "C" void kernel_launch(void* const* d_in, const int* in_sizes, int n_in,
                              void* d_out, int out_size, void* d_ws, size_t ws_size,
                              hipStream_t stream) {
    const float* feats = (const float*)d_in[0];
    const int*   y     = (const int*)d_in[1];
    const float* Wm    = (const float*)d_in[2];
    const float* bias  = (const float*)d_in[3];
    float* out = (float*)d_out;

    char* ws = (char*)d_ws;
    float* ce_accum = (float*)ws;                 // 4 B
    int*   counts   = (int*)(ws + 256);           // 1600 B
    float* var_buf  = (float*)(ws + 2048);        // 1600 B
    float* partial  = (float*)(ws + 4096);        // BSPLIT*E*L*F*4 = 13.1 MB

    hipMemsetAsync(ce_accum, 0, sizeof(float), stream);

    k_counts<<<E, 256, 0, stream>>>(y, counts);
    k_sums<<<BSPLIT * NFC * E, 256, 0, stream>>>(feats, y, partial);
    k_var<<<E * L, 256, 0, stream>>>(partial, counts, var_buf);
    k_gemm_ce<<<NROWS / BM, 256, 0, stream>>>(feats, Wm, bias, y, ce_accum);
    k_final<<<1, 128, 0, stream>>>(counts, var_buf, ce_accum, out);
}

// Round 2
// 706.013 us; speedup vs baseline: 1.2744x; 1.2744x over previous
//
#include <hip/hip_runtime.h>
#include <hip/hip_bf16.h>
#include <math.h>

#define E 4
#define B 8192
#define F 2048
#define L 100
#define NROWS (E * B)          // 32768
#define LAMBDA 1.0f

typedef __attribute__((ext_vector_type(8))) short bf16x8;
typedef __attribute__((ext_vector_type(4))) float f32x4;

static __device__ inline unsigned short f2bf(float x) {
    unsigned u = __float_as_uint(x);
    unsigned r = (u + 0x7FFFu + ((u >> 16) & 1u)) >> 16;   // RNE
    return (unsigned short)r;
}

// ---------------- K1: per-env label histogram -> counts[E*L] ----------------
__global__ void k_counts(const int* __restrict__ y, int* __restrict__ counts) {
    __shared__ int hist[L];
    int e = blockIdx.x;
    for (int i = threadIdx.x; i < L; i += blockDim.x) hist[i] = 0;
    __syncthreads();
    for (int b = threadIdx.x; b < B; b += blockDim.x)
        atomicAdd(&hist[y[e * B + b]], 1);
    __syncthreads();
    for (int i = threadIdx.x; i < L; i += blockDim.x)
        counts[e * L + i] = hist[i];
}

// --------- K2: W[2048][100] f32 -> Wt[128][2048] bf16 (transposed+pad) ------
__global__ void __launch_bounds__(256) k_prep(const float* __restrict__ W,
                                              unsigned short* __restrict__ Wt) {
    int g = blockIdx.x * 256 + threadIdx.x;   // 65536 threads, 4 k-elems each
    int n = g >> 9;                 // 0..127
    int k = (g & 511) * 4;          // 0..2044
    ushort4 v;
    if (n < L) {
        v.x = f2bf(W[(size_t)(k + 0) * L + n]);
        v.y = f2bf(W[(size_t)(k + 1) * L + n]);
        v.z = f2bf(W[(size_t)(k + 2) * L + n]);
        v.w = f2bf(W[(size_t)(k + 3) * L + n]);
    } else {
        v.x = v.y = v.z = v.w = 0;
    }
    *(ushort4*)&Wt[(size_t)n * F + k] = v;
}

// ---- K3: label-masked sums. Grid = E * (F/64) * 8 = 1024 blocks. -----------
// Block: env e, feature chunk [fc*64, fc*64+64), batch slice of 1024 rows.
// lane <-> stride-1 feature: LDS atomic adds are 2-way bank (free); global
// loads are 256B/wave coalesced. 4 blocks/CU, 16 waves/CU.
#define SFC 64
#define SBS 8
#define SROWS (B / SBS)   // 1024
__global__ void __launch_bounds__(256) k_sums(const float* __restrict__ feats,
                                              const int* __restrict__ y,
                                              float* __restrict__ sums) {
    __shared__ float acc[L * SFC];   // 25600 B
    __shared__ int ys[SROWS];        // 4096 B
    int bi = blockIdx.x;
    int bs = bi & 7;
    int fc = (bi >> 3) & 31;
    int e  = bi >> 8;
    int t = threadIdx.x;
    int wave = t >> 6, lane = t & 63;

    for (int i = t; i < L * SFC; i += 256) acc[i] = 0.f;
    for (int i = t; i < SROWS; i += 256) ys[i] = y[e * B + bs * SROWS + i];
    __syncthreads();

    // wave handles contiguous 256-row slice, 8-row unroll
    const float* fp = feats + (size_t)e * B * F
                            + (size_t)(bs * SROWS + wave * 256) * F
                            + fc * SFC + lane;
    int ybase = wave * 256;
    for (int i = 0; i < 256; i += 8) {
        float x[8];
        int lb[8];
#pragma unroll
        for (int j = 0; j < 8; ++j) x[j] = fp[(size_t)(i + j) * F];
#pragma unroll
        for (int j = 0; j < 8; ++j) lb[j] = ys[ybase + i + j];
#pragma unroll
        for (int j = 0; j < 8; ++j)
            atomicAdd(&acc[lb[j] * SFC + lane], x[j]);
    }
    __syncthreads();

    // flush to global sums[e][l][f] (zero-initialized by memset)
    for (int i = t; i < L * SFC; i += 256) {
        int l = i >> 6, f = i & 63;
        atomicAdd(&sums[((size_t)e * L + l) * F + fc * SFC + f], acc[i]);
    }
}

// -------- K4: sums -> per-(e,l) variance over feature dim -------------------
__global__ void k_var(const float* __restrict__ sums,
                      const int* __restrict__ counts,
                      float* __restrict__ var_out) {
    int el = blockIdx.x;  // e*L + l
    int t = threadIdx.x;
    float inv = 1.f / fmaxf((float)counts[el], 1.f);
    float sm = 0.f, sm2 = 0.f;
    for (int f = t; f < F; f += 256) {
        float m = sums[(size_t)el * F + f] * inv;
        sm += m; sm2 += m * m;
    }
    __shared__ float r1[256], r2[256];
    r1[t] = sm; r2[t] = sm2;
    __syncthreads();
    for (int s = 128; s > 0; s >>= 1) {
        if (t < s) { r1[t] += r1[t + s]; r2[t] += r2[t + s]; }
        __syncthreads();
    }
    if (t == 0) {
        float S = r1[0], S2 = r2[0];
        var_out[el] = (S2 - S * S / (float)F) / (float)(F - 1);
    }
}

// ------- K5: bf16 MFMA GEMM (32768x2048 @ 2048x128pad) + fused CE -----------
#define GBM 128
#define GKC 64
#define APAD 72   // 64 + 8 bf16 elems: even bank-quad spread for b128

__global__ void __launch_bounds__(256) k_gemm_ce(const float* __restrict__ feats,
                                                 const unsigned short* __restrict__ Wt,
                                                 const float* __restrict__ bias,
                                                 const int* __restrict__ y,
                                                 float* __restrict__ ce_accum) {
    __shared__ __align__(16) unsigned short As[GBM * APAD]; // 18432 B
    __shared__ __align__(16) unsigned short Ws[GBM * APAD]; // 18432 B
    __shared__ float red[4];
    int t = threadIdx.x;
    int wave = t >> 6, lane = t & 63;
    int quad = lane >> 4, l16 = lane & 15;
    size_t row0 = (size_t)blockIdx.x * GBM;

    f32x4 acc[2][8];
#pragma unroll
    for (int mt = 0; mt < 2; ++mt)
#pragma unroll
        for (int nt = 0; nt < 8; ++nt)
            acc[mt][nt] = (f32x4){0.f, 0.f, 0.f, 0.f};

    int arow_t = t >> 2;   // 0..63 (two passes of 64 rows)
    int aq = t & 3;        // 16-float quarter of the 64-k chunk
    int wn = t >> 1;       // 0..127
    int wh = t & 1;        // 32-elem half

    for (int k0 = 0; k0 < F; k0 += GKC) {
        // ---- stage A: feats f32 -> bf16 LDS [row][k] pad 72 ----
#pragma unroll
        for (int p = 0; p < 2; ++p) {
            int row = p * 64 + arow_t;
            const float* src = feats + (row0 + row) * (size_t)F + k0 + aq * 16;
            float4 v0 = ((const float4*)src)[0];
            float4 v1 = ((const float4*)src)[1];
            float4 v2 = ((const float4*)src)[2];
            float4 v3 = ((const float4*)src)[3];
            bf16x8 o0, o1;
            o0[0] = f2bf(v0.x); o0[1] = f2bf(v0.y); o0[2] = f2bf(v0.z); o0[3] = f2bf(v0.w);
            o0[4] = f2bf(v1.x); o0[5] = f2bf(v1.y); o0[6] = f2bf(v1.z); o0[7] = f2bf(v1.w);
            o1[0] = f2bf(v2.x); o1[1] = f2bf(v2.y); o1[2] = f2bf(v2.z); o1[3] = f2bf(v2.w);
            o1[4] = f2bf(v3.x); o1[5] = f2bf(v3.y); o1[6] = f2bf(v3.z); o1[7] = f2bf(v3.w);
            *(bf16x8*)&As[row * APAD + aq * 16] = o0;
            *(bf16x8*)&As[row * APAD + aq * 16 + 8] = o1;
        }
        // ---- stage W: Wt bf16 [n][k] -> LDS [n][k] pad 72 ----
        {
            const unsigned short* src = Wt + (size_t)wn * F + k0 + wh * 32;
#pragma unroll
            for (int i = 0; i < 4; ++i) {
                uint4 w = ((const uint4*)src)[i];
                *(uint4*)&Ws[wn * APAD + wh * 32 + i * 8] = w;
            }
        }
        __syncthreads();
        // ---- MFMA: 2 k-steps of 32 ----
#pragma unroll
        for (int ks = 0; ks < 2; ++ks) {
            bf16x8 af[2];
#pragma unroll
            for (int mt = 0; mt < 2; ++mt)
                af[mt] = *(const bf16x8*)&As[(wave * 32 + mt * 16 + l16) * APAD + ks * 32 + quad * 8];
#pragma unroll
            for (int nt = 0; nt < 8; ++nt) {
                bf16x8 bfg = *(const bf16x8*)&Ws[(nt * 16 + l16) * APAD + ks * 32 + quad * 8];
                acc[0][nt] = __builtin_amdgcn_mfma_f32_16x16x32_bf16(af[0], bfg, acc[0][nt], 0, 0, 0);
                acc[1][nt] = __builtin_amdgcn_mfma_f32_16x16x32_bf16(af[1], bfg, acc[1][nt], 0, 0, 0);
            }
        }
        __syncthreads();
    }

    // ---- fused softmax-CE epilogue, all in-register ----
    float bv[8];
#pragma unroll
    for (int nt = 0; nt < 8; ++nt) {
        int c = nt * 16 + l16;
        bv[nt] = (c < L) ? bias[c] : 0.f;
    }
    float lsum = 0.f;
#pragma unroll
    for (int mt = 0; mt < 2; ++mt) {
#pragma unroll
        for (int r = 0; r < 4; ++r) {
            int grow = (int)row0 + wave * 32 + mt * 16 + quad * 4 + r;
            float vv[8];
            float vm = -1e30f;
#pragma unroll
            for (int nt = 0; nt < 8; ++nt) {
                int c = nt * 16 + l16;
                float v = acc[mt][nt][r] + bv[nt];
                vv[nt] = v;
                if (c < L) vm = fmaxf(vm, v);
            }
#pragma unroll
            for (int s = 1; s < 16; s <<= 1) vm = fmaxf(vm, __shfl_xor(vm, s));
            float se = 0.f;
#pragma unroll
            for (int nt = 0; nt < 8; ++nt) {
                int c = nt * 16 + l16;
                if (c < L) se += __expf(vv[nt] - vm);
            }
#pragma unroll
            for (int s = 1; s < 16; s <<= 1) se += __shfl_xor(se, s);
            int lab = y[grow];
            float tv = 0.f;
#pragma unroll
            for (int nt = 0; nt < 8; ++nt) {
                int c = nt * 16 + l16;
                if (c == lab) tv = vv[nt];
            }
#pragma unroll
            for (int s = 1; s < 16; s <<= 1) tv += __shfl_xor(tv, s);
            if (l16 == 0) lsum += vm + __logf(se) - tv;
        }
    }
    lsum += __shfl_xor(lsum, 16);
    lsum += __shfl_xor(lsum, 32);
    if (lane == 0) red[wave] = lsum;
    __syncthreads();
    if (t == 0) atomicAdd(ce_accum, red[0] + red[1] + red[2] + red[3]);
}

// ------------------------- K6: final scalar combine -------------------------
__global__ void k_final(const int* __restrict__ counts,
                        const float* __restrict__ var_in,
                        const float* __restrict__ ce_accum,
                        float* __restrict__ out) {
    __shared__ float s_sum[128], s_cnt[128];
    int t = threadIdx.x;
    float selsum = 0.f, selcnt = 0.f;
    for (int l = t; l < L; l += 128) {
        float nvis = 0.f, vsum = 0.f;
        for (int e = 0; e < E; ++e) {
            if (counts[e * L + l] > 0) { nvis += 1.f; vsum += var_in[e * L + l]; }
        }
        float per_label = vsum / fmaxf(nvis, 1.f);
        if (nvis > 1.5f) { selsum += per_label; selcnt += 1.f; }
    }
    s_sum[t] = selsum; s_cnt[t] = selcnt;
    __syncthreads();
    for (int s = 64; s > 0; s >>= 1) {
        if (t < s) { s_sum[t] += s_sum[t + s]; s_cnt[t] += s_cnt[t + s]; }
        __syncthreads();
    }
    if (t == 0) {
        float mean_loss = LAMBDA * s_sum[0] / fmaxf(s_cnt[0], 1.f);
        float ce = ce_accum[0] / (float)NROWS;
        out[0] = mean_loss + ce;
    }
}

extern "C" void kernel_launch(void* const* d_in, const int* in_sizes, int n_in,
                              void* d_out, int out_size, void* d_ws, size_t ws_size,
                              hipStream_t stream) {
    const float* feats = (const float*)d_in[0];
    const int*   y     = (const int*)d_in[1];
    const float* Wm    = (const float*)d_in[2];
    const float* bias  = (const float*)d_in[3];
    float* out = (float*)d_out;

    char* ws = (char*)d_ws;
    float*          ce_accum = (float*)ws;                  // 4 B
    int*            counts   = (int*)(ws + 256);            // 1600 B
    float*          var_buf  = (float*)(ws + 2048);         // 1600 B
    float*          sums     = (float*)(ws + 4096);         // 3,276,800 B
    unsigned short* Wt       = (unsigned short*)(ws + 4096 + (size_t)E * L * F * 4); // 524,288 B

    hipMemsetAsync(ce_accum, 0, sizeof(float), stream);
    hipMemsetAsync(sums, 0, (size_t)E * L * F * sizeof(float), stream);

    k_prep<<<256, 256, 0, stream>>>(Wm, Wt);
    k_counts<<<E, 256, 0, stream>>>(y, counts);
    k_sums<<<E * (F / SFC) * SBS, 256, 0, stream>>>(feats, y, sums);
    k_gemm_ce<<<NROWS / GBM, 256, 0, stream>>>(feats, Wt, bias, y, ce_accum);
    k_var<<<E * L, 256, 0, stream>>>(sums, counts, var_buf);
    k_final<<<1, 128, 0, stream>>>(counts, var_buf, ce_accum, out);
}

// Round 3
// 476.765 us; speedup vs baseline: 1.8872x; 1.4808x over previous
//
#include <hip/hip_runtime.h>
#include <hip/hip_bf16.h>
#include <math.h>

#define E 4
#define B 8192
#define F 2048
#define L 100
#define NROWS (E * B)          // 32768
#define LAMBDA 1.0f

typedef __attribute__((ext_vector_type(8))) short bf16x8;
typedef __attribute__((ext_vector_type(4))) float f32x4;

static __device__ inline unsigned short f2bf(float x) {
    unsigned u = __float_as_uint(x);
    unsigned r = (u + 0x7FFFu + ((u >> 16) & 1u)) >> 16;   // RNE
    return (unsigned short)r;
}

// --------- K1: W[2048][100] f32 -> Wt[128][2048] bf16 (transposed+pad) ------
__global__ void __launch_bounds__(256) k_prep(const float* __restrict__ W,
                                              unsigned short* __restrict__ Wt) {
    int g = blockIdx.x * 256 + threadIdx.x;   // 65536 threads, 4 k-elems each
    int n = g >> 9;                 // 0..127
    int k = (g & 511) * 4;          // 0..2044
    ushort4 v;
    if (n < L) {
        v.x = f2bf(W[(size_t)(k + 0) * L + n]);
        v.y = f2bf(W[(size_t)(k + 1) * L + n]);
        v.z = f2bf(W[(size_t)(k + 2) * L + n]);
        v.w = f2bf(W[(size_t)(k + 3) * L + n]);
    } else {
        v.x = v.y = v.z = v.w = 0;
    }
    *(ushort4*)&Wt[(size_t)n * F + k] = v;
}

// ---- K2: label-bucket gather sums. Full-row contiguous reads. --------------
// Block = (env e, batch slice of 1024 rows, group of 4 labels). Rows whose
// label is in-group are listed, then streamed whole-row (512 thr x float4 =
// 8 KB = one row) into register accumulators (label fixed per bucket -> no
// LDS RMW). One atomic flush per bucket. Also produces counts.
#define SG 4
#define NSG 25                 // 25 * 4 = 100 labels
#define SBS 8
#define SRW (B / SBS)          // 1024 rows per slice

__global__ void __launch_bounds__(512) k_sums(const float* __restrict__ feats,
                                              const int* __restrict__ y,
                                              float* __restrict__ sums,
                                              int* __restrict__ counts) {
    __shared__ int ys[SRW];                    // 4 KB
    __shared__ unsigned short lists[SG][SRW];  // 8 KB
    __shared__ int cnt[SG];
    int bi = blockIdx.x;
    int lg = bi % NSG;
    int bs = (bi / NSG) % SBS;
    int e  = bi / (NSG * SBS);
    int t = threadIdx.x;
    int lab0 = lg * SG;

    if (t < SG) cnt[t] = 0;
    const int* yb = y + e * B + bs * SRW;
    ys[t] = yb[t];
    ys[t + 512] = yb[t + 512];
    __syncthreads();

    for (int r = t; r < SRW; r += 512) {
        int lb = ys[r] - lab0;
        if ((unsigned)lb < SG) {
            int p = atomicAdd(&cnt[lb], 1);
            lists[lb][p] = (unsigned short)r;
        }
    }
    __syncthreads();

    const float* fb = feats + ((size_t)e * B + (size_t)bs * SRW) * F + t * 4;
#pragma unroll
    for (int lb = 0; lb < SG; ++lb) {
        int n = cnt[lb];
        float4 a0 = make_float4(0.f, 0.f, 0.f, 0.f);
        float4 a1 = make_float4(0.f, 0.f, 0.f, 0.f);
        int i = 0;
        for (; i + 2 <= n; i += 2) {
            int r0 = lists[lb][i];
            int r1 = lists[lb][i + 1];
            float4 x0 = *(const float4*)(fb + (size_t)r0 * F);
            float4 x1 = *(const float4*)(fb + (size_t)r1 * F);
            a0.x += x0.x; a0.y += x0.y; a0.z += x0.z; a0.w += x0.w;
            a1.x += x1.x; a1.y += x1.y; a1.z += x1.z; a1.w += x1.w;
        }
        if (i < n) {
            int r0 = lists[lb][i];
            float4 x0 = *(const float4*)(fb + (size_t)r0 * F);
            a0.x += x0.x; a0.y += x0.y; a0.z += x0.z; a0.w += x0.w;
        }
        if (n > 0) {
            float4 s;
            s.x = a0.x + a1.x; s.y = a0.y + a1.y;
            s.z = a0.z + a1.z; s.w = a0.w + a1.w;
            float* dst = sums + ((size_t)e * L + lab0 + lb) * F + t * 4;
            atomicAdd(dst + 0, s.x);
            atomicAdd(dst + 1, s.y);
            atomicAdd(dst + 2, s.z);
            atomicAdd(dst + 3, s.w);
        }
    }
    if (t < SG) atomicAdd(&counts[e * L + lab0 + t], cnt[t]);
}

// -------- K3: sums -> per-(e,l) variance over feature dim -------------------
__global__ void k_var(const float* __restrict__ sums,
                      const int* __restrict__ counts,
                      float* __restrict__ var_out) {
    int el = blockIdx.x;  // e*L + l
    int t = threadIdx.x;
    float inv = 1.f / fmaxf((float)counts[el], 1.f);
    float sm = 0.f, sm2 = 0.f;
    for (int f = t; f < F; f += 256) {
        float m = sums[(size_t)el * F + f] * inv;
        sm += m; sm2 += m * m;
    }
    __shared__ float r1[256], r2[256];
    r1[t] = sm; r2[t] = sm2;
    __syncthreads();
    for (int s = 128; s > 0; s >>= 1) {
        if (t < s) { r1[t] += r1[t + s]; r2[t] += r2[t + s]; }
        __syncthreads();
    }
    if (t == 0) {
        float S = r1[0], S2 = r2[0];
        var_out[el] = (S2 - S * S / (float)F) / (float)(F - 1);
    }
}

// ------- K4: bf16 MFMA GEMM (32768x2048 @ 2048x128pad) + fused CE -----------
// Operand swap vs R2: A = Wt (M-dim = logit cols, W-frags amortized across
// 16 rows/wave), B = feats rows (N-dim). Both fragments contiguous b128.
// D[m=col][n=row]: lane&15 = row, col = 16*ct + quad*4 + reg.
#define GBM 128
#define GKC 64
#define APAD 72   // 64 + 8 bf16 elems

__global__ void __launch_bounds__(512) k_gemm_ce(const float* __restrict__ feats,
                                                 const unsigned short* __restrict__ Wt,
                                                 const float* __restrict__ bias,
                                                 const int* __restrict__ y,
                                                 float* __restrict__ ce_accum) {
    __shared__ __align__(16) unsigned short As[GBM * APAD]; // 18432 B
    __shared__ __align__(16) unsigned short Ws[GBM * APAD]; // 18432 B
    __shared__ float red[8];
    int t = threadIdx.x;
    int wave = t >> 6, lane = t & 63;
    int quad = lane >> 4, l16 = lane & 15;
    size_t row0 = (size_t)blockIdx.x * GBM;

    f32x4 acc[8];
#pragma unroll
    for (int ct = 0; ct < 8; ++ct) acc[ct] = (f32x4){0.f, 0.f, 0.f, 0.f};

    int srow = t >> 2;   // 0..127
    int sq = t & 3;      // 16-elem quarter of the 64-k chunk

    const float* aptr = feats + (row0 + srow) * (size_t)F + sq * 16;
    const unsigned short* wptr = Wt + (size_t)srow * F + sq * 16;

    // prefetch k0 = 0
    float4 pa[4];
    uint4 pw[2];
#pragma unroll
    for (int i = 0; i < 4; ++i) pa[i] = ((const float4*)aptr)[i];
#pragma unroll
    for (int i = 0; i < 2; ++i) pw[i] = ((const uint4*)wptr)[i];

    for (int k0 = 0; k0 < F; k0 += GKC) {
        // stage prefetched regs -> LDS (A: f32 -> bf16)
        bf16x8 o0, o1;
        o0[0] = f2bf(pa[0].x); o0[1] = f2bf(pa[0].y); o0[2] = f2bf(pa[0].z); o0[3] = f2bf(pa[0].w);
        o0[4] = f2bf(pa[1].x); o0[5] = f2bf(pa[1].y); o0[6] = f2bf(pa[1].z); o0[7] = f2bf(pa[1].w);
        o1[0] = f2bf(pa[2].x); o1[1] = f2bf(pa[2].y); o1[2] = f2bf(pa[2].z); o1[3] = f2bf(pa[2].w);
        o1[4] = f2bf(pa[3].x); o1[5] = f2bf(pa[3].y); o1[6] = f2bf(pa[3].z); o1[7] = f2bf(pa[3].w);
        *(bf16x8*)&As[srow * APAD + sq * 16] = o0;
        *(bf16x8*)&As[srow * APAD + sq * 16 + 8] = o1;
        *(uint4*)&Ws[srow * APAD + sq * 16] = pw[0];
        *(uint4*)&Ws[srow * APAD + sq * 16 + 8] = pw[1];
        __syncthreads();

        // issue next k0's global loads (overlap with MFMA below)
        if (k0 + GKC < F) {
            const float* ap = aptr + k0 + GKC;
            const unsigned short* wp = wptr + k0 + GKC;
#pragma unroll
            for (int i = 0; i < 4; ++i) pa[i] = ((const float4*)ap)[i];
#pragma unroll
            for (int i = 0; i < 2; ++i) pw[i] = ((const uint4*)wp)[i];
        }

#pragma unroll
        for (int ks = 0; ks < 2; ++ks) {
            bf16x8 bfr = *(const bf16x8*)&As[(wave * 16 + l16) * APAD + ks * 32 + quad * 8];
#pragma unroll
            for (int ct = 0; ct < 8; ++ct) {
                bf16x8 af = *(const bf16x8*)&Ws[(ct * 16 + l16) * APAD + ks * 32 + quad * 8];
                acc[ct] = __builtin_amdgcn_mfma_f32_16x16x32_bf16(af, bfr, acc[ct], 0, 0, 0);
            }
        }
        __syncthreads();
    }

    // ---- fused softmax-CE epilogue ----
    int grow = (int)row0 + wave * 16 + l16;
    int lab = y[grow];
    float vv[8][4];
    float vm = -1e30f;
#pragma unroll
    for (int ct = 0; ct < 8; ++ct) {
#pragma unroll
        for (int r = 0; r < 4; ++r) {
            int c = ct * 16 + quad * 4 + r;
            float bb = (c < L) ? bias[c] : 0.f;
            float v = acc[ct][r] + bb;
            vv[ct][r] = v;
            if (c < L) vm = fmaxf(vm, v);
        }
    }
    vm = fmaxf(vm, __shfl_xor(vm, 16));
    vm = fmaxf(vm, __shfl_xor(vm, 32));
    float se = 0.f;
    float tv = 0.f;
#pragma unroll
    for (int ct = 0; ct < 8; ++ct) {
#pragma unroll
        for (int r = 0; r < 4; ++r) {
            int c = ct * 16 + quad * 4 + r;
            if (c < L) se += __expf(vv[ct][r] - vm);
            if (c == lab) tv = vv[ct][r];
        }
    }
    se += __shfl_xor(se, 16);
    se += __shfl_xor(se, 32);
    tv += __shfl_xor(tv, 16);
    tv += __shfl_xor(tv, 32);
    float ce = vm + __logf(se) - tv;   // per-row value, all quads agree
#pragma unroll
    for (int s = 1; s <= 8; s <<= 1) ce += __shfl_xor(ce, s);  // sum 16 rows
    if (lane == 0) red[wave] = ce;
    __syncthreads();
    if (t == 0) {
        float v = 0.f;
#pragma unroll
        for (int w = 0; w < 8; ++w) v += red[w];
        atomicAdd(ce_accum, v);
    }
}

// ------------------------- K5: final scalar combine -------------------------
__global__ void k_final(const int* __restrict__ counts,
                        const float* __restrict__ var_in,
                        const float* __restrict__ ce_accum,
                        float* __restrict__ out) {
    __shared__ float s_sum[128], s_cnt[128];
    int t = threadIdx.x;
    float selsum = 0.f, selcnt = 0.f;
    for (int l = t; l < L; l += 128) {
        float nvis = 0.f, vsum = 0.f;
        for (int e = 0; e < E; ++e) {
            if (counts[e * L + l] > 0) { nvis += 1.f; vsum += var_in[e * L + l]; }
        }
        float per_label = vsum / fmaxf(nvis, 1.f);
        if (nvis > 1.5f) { selsum += per_label; selcnt += 1.f; }
    }
    s_sum[t] = selsum; s_cnt[t] = selcnt;
    __syncthreads();
    for (int s = 64; s > 0; s >>= 1) {
        if (t < s) { s_sum[t] += s_sum[t + s]; s_cnt[t] += s_cnt[t + s]; }
        __syncthreads();
    }
    if (t == 0) {
        float mean_loss = LAMBDA * s_sum[0] / fmaxf(s_cnt[0], 1.f);
        float ce = ce_accum[0] / (float)NROWS;
        out[0] = mean_loss + ce;
    }
}

extern "C" void kernel_launch(void* const* d_in, const int* in_sizes, int n_in,
                              void* d_out, int out_size, void* d_ws, size_t ws_size,
                              hipStream_t stream) {
    const float* feats = (const float*)d_in[0];
    const int*   y     = (const int*)d_in[1];
    const float* Wm    = (const float*)d_in[2];
    const float* bias  = (const float*)d_in[3];
    float* out = (float*)d_out;

    char* ws = (char*)d_ws;
    float*          ce_accum = (float*)ws;                  // 4 B
    int*            counts   = (int*)(ws + 256);            // 1600 B
    float*          var_buf  = (float*)(ws + 2048);         // 1600 B
    float*          sums     = (float*)(ws + 4096);         // 3,276,800 B
    unsigned short* Wt       = (unsigned short*)(ws + 4096 + (size_t)E * L * F * 4); // 524,288 B

    hipMemsetAsync(ce_accum, 0, sizeof(float), stream);
    hipMemsetAsync(counts, 0, E * L * sizeof(int), stream);
    hipMemsetAsync(sums, 0, (size_t)E * L * F * sizeof(float), stream);

    k_prep<<<256, 256, 0, stream>>>(Wm, Wt);
    k_sums<<<E * SBS * NSG, 512, 0, stream>>>(feats, y, sums, counts);
    k_gemm_ce<<<NROWS / GBM, 512, 0, stream>>>(feats, Wt, bias, y, ce_accum);
    k_var<<<E * L, 256, 0, stream>>>(sums, counts, var_buf);
    k_final<<<1, 128, 0, stream>>>(counts, var_buf, ce_accum, out);
}

// Round 4
// 438.254 us; speedup vs baseline: 2.0531x; 1.0879x over previous
//
#include <hip/hip_runtime.h>
#include <hip/hip_bf16.h>
#include <math.h>

#define E 4
#define B 8192
#define F 2048
#define L 100
#define NROWS (E * B)          // 32768
#define LAMBDA 1.0f

typedef __attribute__((ext_vector_type(8))) short bf16x8;
typedef __attribute__((ext_vector_type(4))) float f32x4;

static __device__ inline unsigned short f2bf(float x) {
    unsigned u = __float_as_uint(x);
    unsigned r = (u + 0x7FFFu + ((u >> 16) & 1u)) >> 16;   // RNE
    return (unsigned short)r;
}

// ---- sums geometry ----
#define SG 4
#define NSG 25                 // 25 * 4 = 100 labels
#define SBS 8
#define SRW (B / SBS)          // 1024 rows per slice
#define NSUM (E * SBS * NSG)   // 800 blocks

// ---- gemm geometry ----
#define GBM 128                // feats rows per block (N-dim)
#define GNC 112                // logit cols padded 100->112 (M-dim, 7 tiles)
#define GKC 64
#define APAD 72
#define NGEMM (NROWS / GBM)    // 256 blocks

// --------- K1: W[2048][100] f32 -> Wt[112][2048] bf16 (transposed+pad) ------
__global__ void __launch_bounds__(256) k_prep(const float* __restrict__ W,
                                              unsigned short* __restrict__ Wt) {
    int g = blockIdx.x * 256 + threadIdx.x;   // 57344 threads, 4 k-elems each
    int n = g >> 9;                 // 0..111
    int k = (g & 511) * 4;          // 0..2044
    ushort4 v;
    if (n < L) {
        v.x = f2bf(W[(size_t)(k + 0) * L + n]);
        v.y = f2bf(W[(size_t)(k + 1) * L + n]);
        v.z = f2bf(W[(size_t)(k + 2) * L + n]);
        v.w = f2bf(W[(size_t)(k + 3) * L + n]);
    } else {
        v.x = v.y = v.z = v.w = 0;
    }
    *(ushort4*)&Wt[(size_t)n * F + k] = v;
}

// ---- K2: merged main kernel. Blocks [0,256) = MFMA gemm+CE over 128 rows;
// blocks [256,1056) = label-bucket gather sums over (env, slice, 4-label grp).
// One CU co-hosts one of each (LDS 34.6KB x2, 16 waves): MFMA overlaps the
// sums blocks' pure HBM streaming; feats is read exactly twice total.
__global__ void __launch_bounds__(512, 4) k_main(const float* __restrict__ feats,
                                                 const int* __restrict__ y,
                                                 const unsigned short* __restrict__ Wt,
                                                 const float* __restrict__ bias,
                                                 float* __restrict__ partial,
                                                 int* __restrict__ counts,
                                                 float* __restrict__ ce_accum) {
    __shared__ __align__(16) char sm[34624];
    int t = threadIdx.x;

    if (blockIdx.x < NGEMM) {
        // ================= GEMM + CE =================
        unsigned short* As = (unsigned short*)sm;            // 128*72*2 = 18432
        unsigned short* Ws = As + GBM * APAD;                // 112*72*2 = 16128
        float* red = (float*)(sm + 34560);                   // 8 floats
        int wave = t >> 6, lane = t & 63;
        int quad = lane >> 4, l16 = lane & 15;
        size_t row0 = (size_t)blockIdx.x * GBM;

        f32x4 acc[7];
#pragma unroll
        for (int ct = 0; ct < 7; ++ct) acc[ct] = (f32x4){0.f, 0.f, 0.f, 0.f};

        int srow = t >> 2;   // 0..127
        int sq = t & 3;      // 16-elem quarter of the 64-k chunk

        const float* aptr = feats + (row0 + srow) * (size_t)F + sq * 16;
        const unsigned short* wptr = Wt + (size_t)srow * F + sq * 16;

        float4 pa[4];
        uint4 pw[2];
#pragma unroll
        for (int i = 0; i < 4; ++i) pa[i] = ((const float4*)aptr)[i];
        if (srow < GNC) {
#pragma unroll
            for (int i = 0; i < 2; ++i) pw[i] = ((const uint4*)wptr)[i];
        }

        for (int k0 = 0; k0 < F; k0 += GKC) {
            bf16x8 o0, o1;
            o0[0] = f2bf(pa[0].x); o0[1] = f2bf(pa[0].y); o0[2] = f2bf(pa[0].z); o0[3] = f2bf(pa[0].w);
            o0[4] = f2bf(pa[1].x); o0[5] = f2bf(pa[1].y); o0[6] = f2bf(pa[1].z); o0[7] = f2bf(pa[1].w);
            o1[0] = f2bf(pa[2].x); o1[1] = f2bf(pa[2].y); o1[2] = f2bf(pa[2].z); o1[3] = f2bf(pa[2].w);
            o1[4] = f2bf(pa[3].x); o1[5] = f2bf(pa[3].y); o1[6] = f2bf(pa[3].z); o1[7] = f2bf(pa[3].w);
            *(bf16x8*)&As[srow * APAD + sq * 16] = o0;
            *(bf16x8*)&As[srow * APAD + sq * 16 + 8] = o1;
            if (srow < GNC) {
                *(uint4*)&Ws[srow * APAD + sq * 16] = pw[0];
                *(uint4*)&Ws[srow * APAD + sq * 16 + 8] = pw[1];
            }
            __syncthreads();

            if (k0 + GKC < F) {
                const float* ap = aptr + k0 + GKC;
                const unsigned short* wp = wptr + k0 + GKC;
#pragma unroll
                for (int i = 0; i < 4; ++i) pa[i] = ((const float4*)ap)[i];
                if (srow < GNC) {
#pragma unroll
                    for (int i = 0; i < 2; ++i) pw[i] = ((const uint4*)wp)[i];
                }
            }

#pragma unroll
            for (int ks = 0; ks < 2; ++ks) {
                bf16x8 bfr = *(const bf16x8*)&As[(wave * 16 + l16) * APAD + ks * 32 + quad * 8];
#pragma unroll
                for (int ct = 0; ct < 7; ++ct) {
                    bf16x8 af = *(const bf16x8*)&Ws[(ct * 16 + l16) * APAD + ks * 32 + quad * 8];
                    acc[ct] = __builtin_amdgcn_mfma_f32_16x16x32_bf16(af, bfr, acc[ct], 0, 0, 0);
                }
            }
            __syncthreads();
        }

        // fused softmax-CE epilogue (D: lane&15 = row, col = 16*ct+quad*4+r)
        int grow = (int)row0 + wave * 16 + l16;
        int lab = y[grow];
        float vv[7][4];
        float vm = -1e30f;
#pragma unroll
        for (int ct = 0; ct < 7; ++ct) {
#pragma unroll
            for (int r = 0; r < 4; ++r) {
                int c = ct * 16 + quad * 4 + r;
                float bb = (c < L) ? bias[c] : 0.f;
                float v = acc[ct][r] + bb;
                vv[ct][r] = v;
                if (c < L) vm = fmaxf(vm, v);
            }
        }
        vm = fmaxf(vm, __shfl_xor(vm, 16));
        vm = fmaxf(vm, __shfl_xor(vm, 32));
        float se = 0.f, tv = 0.f;
#pragma unroll
        for (int ct = 0; ct < 7; ++ct) {
#pragma unroll
            for (int r = 0; r < 4; ++r) {
                int c = ct * 16 + quad * 4 + r;
                if (c < L) se += __expf(vv[ct][r] - vm);
                if (c == lab) tv = vv[ct][r];
            }
        }
        se += __shfl_xor(se, 16);
        se += __shfl_xor(se, 32);
        tv += __shfl_xor(tv, 16);
        tv += __shfl_xor(tv, 32);
        float ce = vm + __logf(se) - tv;
#pragma unroll
        for (int s = 1; s <= 8; s <<= 1) ce += __shfl_xor(ce, s);
        if (lane == 0) red[wave] = ce;
        __syncthreads();
        if (t == 0) {
            float v = 0.f;
#pragma unroll
            for (int w = 0; w < 8; ++w) v += red[w];
            atomicAdd(ce_accum, v);
        }
    } else {
        // ================= label-bucket sums =================
        int* ys = (int*)sm;                                   // 4 KB
        unsigned short (*lists)[SRW] = (unsigned short (*)[SRW])(sm + 4096); // 8 KB
        int* cnt = (int*)(sm + 4096 + 8192);
        int bi = blockIdx.x - NGEMM;
        int lg = bi % NSG;
        int bs = (bi / NSG) % SBS;
        int e  = bi / (NSG * SBS);
        int lab0 = lg * SG;

        if (t < SG) cnt[t] = 0;
        const int* yb = y + e * B + bs * SRW;
        ys[t] = yb[t];
        ys[t + 512] = yb[t + 512];
        __syncthreads();

        for (int r = t; r < SRW; r += 512) {
            int lb = ys[r] - lab0;
            if ((unsigned)lb < SG) {
                int p = atomicAdd(&cnt[lb], 1);
                lists[lb][p] = (unsigned short)r;
            }
        }
        __syncthreads();

        const float* fb = feats + ((size_t)e * B + (size_t)bs * SRW) * F + t * 4;
#pragma unroll
        for (int lb = 0; lb < SG; ++lb) {
            int n = cnt[lb];
            float4 a0 = make_float4(0.f, 0.f, 0.f, 0.f);
            float4 a1 = make_float4(0.f, 0.f, 0.f, 0.f);
            int i = 0;
            for (; i + 2 <= n; i += 2) {
                int r0 = lists[lb][i];
                int r1 = lists[lb][i + 1];
                float4 x0 = *(const float4*)(fb + (size_t)r0 * F);
                float4 x1 = *(const float4*)(fb + (size_t)r1 * F);
                a0.x += x0.x; a0.y += x0.y; a0.z += x0.z; a0.w += x0.w;
                a1.x += x1.x; a1.y += x1.y; a1.z += x1.z; a1.w += x1.w;
            }
            if (i < n) {
                int r0 = lists[lb][i];
                float4 x0 = *(const float4*)(fb + (size_t)r0 * F);
                a0.x += x0.x; a0.y += x0.y; a0.z += x0.z; a0.w += x0.w;
            }
            float4 s;
            s.x = a0.x + a1.x; s.y = a0.y + a1.y;
            s.z = a0.z + a1.z; s.w = a0.w + a1.w;
            // unconditional store: partial is poisoned, must be fully written
            *(float4*)&partial[(((size_t)e * SBS + bs) * L + lab0 + lb) * F + t * 4] = s;
        }
        if (t < SG) atomicAdd(&counts[e * L + lab0 + t], cnt[t]);
    }
}

// -------- K3: partial[e][bs][l][f] -> per-(e,l) variance over feature dim ---
__global__ void k_var(const float* __restrict__ partial,
                      const int* __restrict__ counts,
                      float* __restrict__ var_out) {
    int el = blockIdx.x;  // e*L + l
    int e = el / L, l = el % L;
    int t = threadIdx.x;
    float inv = 1.f / fmaxf((float)counts[el], 1.f);
    float sm = 0.f, sm2 = 0.f;
    for (int f = t; f < F; f += 256) {
        float s = 0.f;
#pragma unroll
        for (int bs = 0; bs < SBS; ++bs)
            s += partial[(((size_t)e * SBS + bs) * L + l) * F + f];
        float m = s * inv;
        sm += m; sm2 += m * m;
    }
    __shared__ float r1[256], r2[256];
    r1[t] = sm; r2[t] = sm2;
    __syncthreads();
    for (int s = 128; s > 0; s >>= 1) {
        if (t < s) { r1[t] += r1[t + s]; r2[t] += r2[t + s]; }
        __syncthreads();
    }
    if (t == 0) {
        float S = r1[0], S2 = r2[0];
        var_out[el] = (S2 - S * S / (float)F) / (float)(F - 1);
    }
}

// ------------------------- K4: final scalar combine -------------------------
__global__ void k_final(const int* __restrict__ counts,
                        const float* __restrict__ var_in,
                        const float* __restrict__ ce_accum,
                        float* __restrict__ out) {
    __shared__ float s_sum[128], s_cnt[128];
    int t = threadIdx.x;
    float selsum = 0.f, selcnt = 0.f;
    for (int l = t; l < L; l += 128) {
        float nvis = 0.f, vsum = 0.f;
        for (int e = 0; e < E; ++e) {
            if (counts[e * L + l] > 0) { nvis += 1.f; vsum += var_in[e * L + l]; }
        }
        float per_label = vsum / fmaxf(nvis, 1.f);
        if (nvis > 1.5f) { selsum += per_label; selcnt += 1.f; }
    }
    s_sum[t] = selsum; s_cnt[t] = selcnt;
    __syncthreads();
    for (int s = 64; s > 0; s >>= 1) {
        if (t < s) { s_sum[t] += s_sum[t + s]; s_cnt[t] += s_cnt[t + s]; }
        __syncthreads();
    }
    if (t == 0) {
        float mean_loss = LAMBDA * s_sum[0] / fmaxf(s_cnt[0], 1.f);
        float ce = ce_accum[0] / (float)NROWS;
        out[0] = mean_loss + ce;
    }
}

extern "C" void kernel_launch(void* const* d_in, const int* in_sizes, int n_in,
                              void* d_out, int out_size, void* d_ws, size_t ws_size,
                              hipStream_t stream) {
    const float* feats = (const float*)d_in[0];
    const int*   y     = (const int*)d_in[1];
    const float* Wm    = (const float*)d_in[2];
    const float* bias  = (const float*)d_in[3];
    float* out = (float*)d_out;

    char* ws = (char*)d_ws;
    float*          ce_accum = (float*)ws;                  // 4 B
    int*            counts   = (int*)(ws + 256);            // 1600 B
    float*          var_buf  = (float*)(ws + 2048);         // 1600 B
    float*          partial  = (float*)(ws + 4096);         // E*SBS*L*F*4 = 26.2 MB
    unsigned short* Wt       = (unsigned short*)(ws + 4096 + (size_t)E * SBS * L * F * 4); // 458 KB

    hipMemsetAsync(ce_accum, 0, sizeof(float), stream);
    hipMemsetAsync(counts, 0, E * L * sizeof(int), stream);

    k_prep<<<(GNC * 512) / 256, 256, 0, stream>>>(Wm, Wt);
    k_main<<<NGEMM + NSUM, 512, 0, stream>>>(feats, y, Wt, bias, partial, counts, ce_accum);
    k_var<<<E * L, 256, 0, stream>>>(partial, counts, var_buf);
    k_final<<<1, 128, 0, stream>>>(counts, var_buf, ce_accum, out);
}

// Round 5
// 435.673 us; speedup vs baseline: 2.0652x; 1.0059x over previous
//
#include <hip/hip_runtime.h>
#include <hip/hip_bf16.h>
#include <math.h>

#define E 4
#define B 8192
#define F 2048
#define L 100
#define NROWS (E * B)          // 32768
#define LAMBDA 1.0f

typedef __attribute__((ext_vector_type(8))) short bf16x8;
typedef __attribute__((ext_vector_type(4))) float f32x4;

static __device__ inline unsigned short f2bf(float x) {
    unsigned u = __float_as_uint(x);
    unsigned r = (u + 0x7FFFu + ((u >> 16) & 1u)) >> 16;   // RNE
    return (unsigned short)r;
}

// ---- sums geometry ----
#define SG 4
#define NSG 25                 // 25 * 4 = 100 labels
#define SBS 8
#define SRW (B / SBS)          // 1024 rows per slice
#define NSUM (E * SBS * NSG)   // 800 blocks

// ---- gemm geometry ----
#define GBM 128                // feats rows per block (N-dim)
#define GNC 112                // logit cols padded 100->112 (M-dim, 7 tiles)
#define GKC 64
#define APAD 72
#define NGEMM (NROWS / GBM)    // 256 blocks

// --------- K1: W[2048][100] f32 -> Wt[112][2048] bf16 (transposed+pad) ------
__global__ void __launch_bounds__(256) k_prep(const float* __restrict__ W,
                                              unsigned short* __restrict__ Wt) {
    int g = blockIdx.x * 256 + threadIdx.x;   // 57344 threads, 4 k-elems each
    int n = g >> 9;                 // 0..111
    int k = (g & 511) * 4;          // 0..2044
    ushort4 v;
    if (n < L) {
        v.x = f2bf(W[(size_t)(k + 0) * L + n]);
        v.y = f2bf(W[(size_t)(k + 1) * L + n]);
        v.z = f2bf(W[(size_t)(k + 2) * L + n]);
        v.w = f2bf(W[(size_t)(k + 3) * L + n]);
    } else {
        v.x = v.y = v.z = v.w = 0;
    }
    *(ushort4*)&Wt[(size_t)n * F + k] = v;
}

// round-half-up pack of two f32 -> packed bf16x2 (hi<<16 | lo)
static __device__ inline unsigned pack_bf(float lo, float hi) {
    unsigned ul = __float_as_uint(lo) + 0x8000u;
    unsigned uh = __float_as_uint(hi) + 0x8000u;
    return __builtin_amdgcn_perm(uh, ul, 0x07060302u);
}

// ---- K2: merged main kernel. Blocks [0,256) = MFMA gemm+CE over 128 rows;
// blocks [256,1056) = tagged-stream label sums over (env, slice, 4-label grp).
__global__ void __launch_bounds__(512, 4) k_main(const float* __restrict__ feats,
                                                 const int* __restrict__ y,
                                                 const unsigned short* __restrict__ Wt,
                                                 const float* __restrict__ bias,
                                                 float* __restrict__ partial,
                                                 int* __restrict__ counts,
                                                 float* __restrict__ ce_accum) {
    __shared__ __align__(16) char sm[34624];
    int t = threadIdx.x;

    if (blockIdx.x < NGEMM) {
        // ================= GEMM + CE =================
        unsigned short* As = (unsigned short*)sm;            // 128*72*2 = 18432
        unsigned short* Ws = As + GBM * APAD;                // 112*72*2 = 16128
        float* red = (float*)(sm + 34560);                   // 8 floats
        int wave = t >> 6, lane = t & 63;
        int quad = lane >> 4, l16 = lane & 15;
        size_t row0 = (size_t)blockIdx.x * GBM;

        f32x4 acc[7];
#pragma unroll
        for (int ct = 0; ct < 7; ++ct) acc[ct] = (f32x4){0.f, 0.f, 0.f, 0.f};

        int srow = t >> 2;   // 0..127
        int sq = t & 3;      // 16-elem quarter of the 64-k chunk

        const float* aptr = feats + (row0 + srow) * (size_t)F + sq * 16;
        const unsigned short* wptr = Wt + (size_t)srow * F + sq * 16;

        float4 pa[4];
        uint4 pw[2];
#pragma unroll
        for (int i = 0; i < 4; ++i) pa[i] = ((const float4*)aptr)[i];
        if (srow < GNC) {
#pragma unroll
            for (int i = 0; i < 2; ++i) pw[i] = ((const uint4*)wptr)[i];
        }

        for (int k0 = 0; k0 < F; k0 += GKC) {
            // stage prefetched regs -> LDS (A: f32 -> bf16 via add+v_perm)
            unsigned u[8];
#pragma unroll
            for (int i = 0; i < 4; ++i) {
                u[i * 2]     = pack_bf(pa[i].x, pa[i].y);
                u[i * 2 + 1] = pack_bf(pa[i].z, pa[i].w);
            }
            *(uint4*)&As[srow * APAD + sq * 16]     = make_uint4(u[0], u[1], u[2], u[3]);
            *(uint4*)&As[srow * APAD + sq * 16 + 8] = make_uint4(u[4], u[5], u[6], u[7]);
            if (srow < GNC) {
                *(uint4*)&Ws[srow * APAD + sq * 16] = pw[0];
                *(uint4*)&Ws[srow * APAD + sq * 16 + 8] = pw[1];
            }
            __syncthreads();

            if (k0 + GKC < F) {
                const float* ap = aptr + k0 + GKC;
                const unsigned short* wp = wptr + k0 + GKC;
#pragma unroll
                for (int i = 0; i < 4; ++i) pa[i] = ((const float4*)ap)[i];
                if (srow < GNC) {
#pragma unroll
                    for (int i = 0; i < 2; ++i) pw[i] = ((const uint4*)wp)[i];
                }
            }

#pragma unroll
            for (int ks = 0; ks < 2; ++ks) {
                bf16x8 bfr = *(const bf16x8*)&As[(wave * 16 + l16) * APAD + ks * 32 + quad * 8];
#pragma unroll
                for (int ct = 0; ct < 7; ++ct) {
                    bf16x8 af = *(const bf16x8*)&Ws[(ct * 16 + l16) * APAD + ks * 32 + quad * 8];
                    acc[ct] = __builtin_amdgcn_mfma_f32_16x16x32_bf16(af, bfr, acc[ct], 0, 0, 0);
                }
            }
            __syncthreads();
        }

        // fused softmax-CE epilogue (D: lane&15 = row, col = 16*ct+quad*4+r)
        int grow = (int)row0 + wave * 16 + l16;
        int lab = y[grow];
        float vv[7][4];
        float vm = -1e30f;
#pragma unroll
        for (int ct = 0; ct < 7; ++ct) {
#pragma unroll
            for (int r = 0; r < 4; ++r) {
                int c = ct * 16 + quad * 4 + r;
                float bb = (c < L) ? bias[c] : 0.f;
                float v = acc[ct][r] + bb;
                vv[ct][r] = v;
                if (c < L) vm = fmaxf(vm, v);
            }
        }
        vm = fmaxf(vm, __shfl_xor(vm, 16));
        vm = fmaxf(vm, __shfl_xor(vm, 32));
        float se = 0.f, tv = 0.f;
#pragma unroll
        for (int ct = 0; ct < 7; ++ct) {
#pragma unroll
            for (int r = 0; r < 4; ++r) {
                int c = ct * 16 + quad * 4 + r;
                if (c < L) se += __expf(vv[ct][r] - vm);
                if (c == lab) tv = vv[ct][r];
            }
        }
        se += __shfl_xor(se, 16);
        se += __shfl_xor(se, 32);
        tv += __shfl_xor(tv, 16);
        tv += __shfl_xor(tv, 32);
        float ce = vm + __logf(se) - tv;
#pragma unroll
        for (int s = 1; s <= 8; s <<= 1) ce += __shfl_xor(ce, s);
        if (lane == 0) red[wave] = ce;
        __syncthreads();
        if (t == 0) {
            float v = 0.f;
#pragma unroll
            for (int w = 0; w < 8; ++w) v += red[w];
            atomicAdd(ce_accum, v);
        }
    } else {
        // ================= tagged-stream label sums =================
        int* ys = (int*)sm;                                   // 4096 B
        unsigned short* list = (unsigned short*)(sm + 4096);  // 2048 B
        int* cnt4 = (int*)(sm + 4096 + 2048);                 // 16 B
        int* ntot = (int*)(sm + 4096 + 2048 + 16);            // 4 B
        int bi = blockIdx.x - NGEMM;
        int lg = bi % NSG;
        int bs = (bi / NSG) % SBS;
        int e  = bi / (NSG * SBS);
        int lab0 = lg * SG;

        if (t < SG) cnt4[t] = 0;
        if (t == 8) ntot[0] = 0;
        const int* yb = y + e * B + bs * SRW;
        ys[t] = yb[t];
        ys[t + 512] = yb[t + 512];
        __syncthreads();

        for (int r = t; r < SRW; r += 512) {
            int lb = ys[r] - lab0;
            if ((unsigned)lb < SG) {
                atomicAdd(&cnt4[lb], 1);
                int p = atomicAdd(ntot, 1);
                list[p] = (unsigned short)(r | (lb << 10));
            }
        }
        __syncthreads();
        int n = ntot[0];
        int npad = (n + 3) & ~3;
        if (t < npad - n) list[n + t] = 0;   // pad rows (guarded out below)
        __syncthreads();

        const float* fb = feats + ((size_t)e * B + (size_t)bs * SRW) * F + t * 4;
        float4 a0 = make_float4(0.f, 0.f, 0.f, 0.f);
        float4 a1 = a0, a2 = a0, a3 = a0;

        float4 x[4];
        int tg[4];
        if (n > 0) {
#pragma unroll
            for (int j = 0; j < 4; ++j) {
                int ev = list[j];
                tg[j] = ev >> 10;
                x[j] = *(const float4*)(fb + (size_t)(ev & 1023) * F);
            }
            for (int i = 0; i < npad; i += 4) {
                float4 nx[4];
                int ntg[4];
                if (i + 4 < npad) {
#pragma unroll
                    for (int j = 0; j < 4; ++j) {
                        int ev = list[i + 4 + j];
                        ntg[j] = ev >> 10;
                        nx[j] = *(const float4*)(fb + (size_t)(ev & 1023) * F);
                    }
                }
#pragma unroll
                for (int j = 0; j < 4; ++j) {
                    if (i + j < n) {   // uniform across block
                        float4 v = x[j];
                        int g = tg[j];  // uniform across block
                        if (g == 0)      { a0.x += v.x; a0.y += v.y; a0.z += v.z; a0.w += v.w; }
                        else if (g == 1) { a1.x += v.x; a1.y += v.y; a1.z += v.z; a1.w += v.w; }
                        else if (g == 2) { a2.x += v.x; a2.y += v.y; a2.z += v.z; a2.w += v.w; }
                        else             { a3.x += v.x; a3.y += v.y; a3.z += v.z; a3.w += v.w; }
                    }
                }
#pragma unroll
                for (int j = 0; j < 4; ++j) { x[j] = nx[j]; tg[j] = ntg[j]; }
            }
        }

        float* pb = partial + (((size_t)e * SBS + bs) * L + lab0) * F + t * 4;
        *(float4*)(pb + 0 * F) = a0;   // unconditional: partial is poisoned
        *(float4*)(pb + 1 * F) = a1;
        *(float4*)(pb + 2 * F) = a2;
        *(float4*)(pb + 3 * F) = a3;
        if (t < SG) atomicAdd(&counts[e * L + lab0 + t], cnt4[t]);
    }
}

// -------- K3: partial[e][bs][l][f] -> per-(e,l) variance over feature dim ---
__global__ void k_var(const float* __restrict__ partial,
                      const int* __restrict__ counts,
                      float* __restrict__ var_out) {
    int el = blockIdx.x;  // e*L + l
    int e = el / L, l = el % L;
    int t = threadIdx.x;
    float inv = 1.f / fmaxf((float)counts[el], 1.f);
    float sm = 0.f, sm2 = 0.f;
    for (int f = t; f < F; f += 256) {
        float s = 0.f;
#pragma unroll
        for (int bs = 0; bs < SBS; ++bs)
            s += partial[(((size_t)e * SBS + bs) * L + l) * F + f];
        float m = s * inv;
        sm += m; sm2 += m * m;
    }
    __shared__ float r1[256], r2[256];
    r1[t] = sm; r2[t] = sm2;
    __syncthreads();
    for (int s = 128; s > 0; s >>= 1) {
        if (t < s) { r1[t] += r1[t + s]; r2[t] += r2[t + s]; }
        __syncthreads();
    }
    if (t == 0) {
        float S = r1[0], S2 = r2[0];
        var_out[el] = (S2 - S * S / (float)F) / (float)(F - 1);
    }
}

// ------------------------- K4: final scalar combine -------------------------
__global__ void k_final(const int* __restrict__ counts,
                        const float* __restrict__ var_in,
                        const float* __restrict__ ce_accum,
                        float* __restrict__ out) {
    __shared__ float s_sum[128], s_cnt[128];
    int t = threadIdx.x;
    float selsum = 0.f, selcnt = 0.f;
    for (int l = t; l < L; l += 128) {
        float nvis = 0.f, vsum = 0.f;
        for (int e = 0; e < E; ++e) {
            if (counts[e * L + l] > 0) { nvis += 1.f; vsum += var_in[e * L + l]; }
        }
        float per_label = vsum / fmaxf(nvis, 1.f);
        if (nvis > 1.5f) { selsum += per_label; selcnt += 1.f; }
    }
    s_sum[t] = selsum; s_cnt[t] = selcnt;
    __syncthreads();
    for (int s = 64; s > 0; s >>= 1) {
        if (t < s) { s_sum[t] += s_sum[t + s]; s_cnt[t] += s_cnt[t + s]; }
        __syncthreads();
    }
    if (t == 0) {
        float mean_loss = LAMBDA * s_sum[0] / fmaxf(s_cnt[0], 1.f);
        float ce = ce_accum[0] / (float)NROWS;
        out[0] = mean_loss + ce;
    }
}

extern "C" void kernel_launch(void* const* d_in, const int* in_sizes, int n_in,
                              void* d_out, int out_size, void* d_ws, size_t ws_size,
                              hipStream_t stream) {
    const float* feats = (const float*)d_in[0];
    const int*   y     = (const int*)d_in[1];
    const float* Wm    = (const float*)d_in[2];
    const float* bias  = (const float*)d_in[3];
    float* out = (float*)d_out;

    char* ws = (char*)d_ws;
    float*          ce_accum = (float*)ws;                  // 4 B
    int*            counts   = (int*)(ws + 256);            // 1600 B
    float*          var_buf  = (float*)(ws + 2048);         // 1600 B
    float*          partial  = (float*)(ws + 4096);         // E*SBS*L*F*4 = 26.2 MB
    unsigned short* Wt       = (unsigned short*)(ws + 4096 + (size_t)E * SBS * L * F * 4); // 458 KB

    hipMemsetAsync(ce_accum, 0, sizeof(float), stream);
    hipMemsetAsync(counts, 0, E * L * sizeof(int), stream);

    k_prep<<<(GNC * 512) / 256, 256, 0, stream>>>(Wm, Wt);
    k_main<<<NGEMM + NSUM, 512, 0, stream>>>(feats, y, Wt, bias, partial, counts, ce_accum);
    k_var<<<E * L, 256, 0, stream>>>(partial, counts, var_buf);
    k_final<<<1, 128, 0, stream>>>(counts, var_buf, ce_accum, out);
}